// Round 4
// baseline (240.881 us; speedup 1.0000x reference)
//
#include <hip/hip_runtime.h>

#define PP 50
#define TPB 256
#define NBATCH 2048
#define GBF 2                    // batches per block
#define NBLKF (NBATCH / GBF)     // 1024 blocks = 4/CU co-resident (68 VGPR, 13KB LDS)
#define NCOPY 32                 // contention-spreading copies for stat atomics
#define NSLOT 30                 // 0-9: BN1 sy/q; 10-14: sum h1; 15-29: sum h1 h1^T
#define NBARC 8                  // spread arrival counters per barrier

static constexpr float EPSF = 1e-5f;
static constexpr double INV_ETOT = 1.0 / 5120000.0;   // 1/(B*P*P)

static __device__ __forceinline__ float lrelu(float x) {
    return fmaxf(x, 0.01f * x);
}
static __device__ __forceinline__ float rfl(float x) {
    return __int_as_float(__builtin_amdgcn_readfirstlane(__float_as_int(x)));
}
// agent-scope (device-coherent) load: safe cross-XCD read of atomically-written stats
static __device__ __forceinline__ double aload(const double* p) {
    return __hip_atomic_load(p, __ATOMIC_RELAXED, __HIP_MEMORY_SCOPE_AGENT);
}

// Two-level spread grid barrier. zone = 256 u32 (zeroed pre-launch):
//   cnt[c] at zone[c*16] (64B apart), done at zone[128], gen at zone[136].
// Arrivals spread over NBARC cachelines (128 RMWs each, parallel), per-counter
// last bumps done; 8th finisher sets gen; everyone polls gen (read-only line).
// Safe: grid (1024) <= co-resident capacity (4/CU * 256, pinned by
// __launch_bounds__(256,4): VGPR<=128, LDS 4x13KB<160KB), and any grid <=
// capacity is fully placed at dispatch (in-order fill of free slots).
static __device__ __forceinline__ void gbar(unsigned* zone) {
    __syncthreads();   // drains each thread's outstanding vmem (incl. atomics)
    if (threadIdx.x == 0) {
        const unsigned c = (unsigned)blockIdx.x & (NBARC - 1u);
        unsigned old = __hip_atomic_fetch_add(&zone[c * 16], 1u,
                           __ATOMIC_ACQ_REL, __HIP_MEMORY_SCOPE_AGENT);
        if (old == (NBLKF / NBARC) - 1u) {
            if (__hip_atomic_fetch_add(&zone[128], 1u,
                    __ATOMIC_ACQ_REL, __HIP_MEMORY_SCOPE_AGENT) == NBARC - 1u) {
                __hip_atomic_store(&zone[136], 1u,
                                   __ATOMIC_RELEASE, __HIP_MEMORY_SCOPE_AGENT);
            }
        }
        while (__hip_atomic_load(&zone[136], __ATOMIC_ACQUIRE,
                                 __HIP_MEMORY_SCOPE_AGENT) == 0u) {
            __builtin_amdgcn_s_sleep(8);
        }
    }
    __syncthreads();
}

// Single fused kernel: phaseA (BN1 stats) -> gbar -> phaseB (h1 moments)
// -> gbar -> phaseC (full MLP, aggregate, rotate, write).
__global__ __launch_bounds__(TPB, 4) void fused_kernel(
    const float* __restrict__ pt,
    const float* __restrict__ feat, const float* __restrict__ ang,
    const float* __restrict__ W1, const float* __restrict__ b1,
    const float* __restrict__ g1, const float* __restrict__ bt1,
    const float* __restrict__ W2, const float* __restrict__ b2,
    const float* __restrict__ g2, const float* __restrict__ bt2,
    const float* __restrict__ W3, const float* __restrict__ b3,
    double* __restrict__ acc, unsigned* __restrict__ bar,
    float* __restrict__ out)
{
    __shared__ float4 nd[GBF * PP];    // (f, ar, ai, -)            i-side
    __shared__ float4 ndj[GBF * PP];   // (f, ar/|a|2, ai/|a|2, -)  j-side
    __shared__ float spt[GBF * PP];
    __shared__ double bacc[GBF][10];
    __shared__ double tmp[NSLOT];
    __shared__ float scsh[2][5];       // sc2, sh2
    __shared__ float red[4][20];
    __shared__ float part[250][5];

    const int t = threadIdx.x;
    const int lane = t & 63;
    const int wv = t >> 6;

    // ---- stage node data (once, reused by all phases) ----
    if (t < GBF * PP) {
        const int idx = blockIdx.x * (GBF * PP) + t;
        float f = feat[idx];
        float2 a2 = ((const float2*)ang)[idx];
        float inv = 1.0f / (a2.x * a2.x + a2.y * a2.y);
        nd[t]  = make_float4(f, a2.x, a2.y, 0.0f);
        ndj[t] = make_float4(f, a2.x * inv, a2.y * inv, 0.0f);
        spt[t] = pt[idx];
    }

    // layer-1 reduced weights (UNfolded; BN1 fold happens in phase B)
    float v0[5], v1[5], v2[5], v3[5], bb1[5];
#pragma unroll
    for (int o = 0; o < 5; ++o) {
        v0[o] = rfl(W1[o*5+0] - W1[o*5+2]);
        v1[o] = rfl(W1[o*5+1] + W1[o*5+2]);
        v2[o] = rfl(W1[o*5+3]);
        v3[o] = rfl(W1[o*5+4]);
        bb1[o] = rfl(b1[o]);
    }

    __syncthreads();

    // ==== phase A: BN1 stats via separable per-batch sums (wave wv = batch wv)
    if (wv < GBF) {
        float f = 0.f, zr = 0.f, zi = 0.f, wr = 0.f, wi = 0.f;
        if (lane < PP) {
            const int node = wv * PP + lane;
            const float4 ni = nd[node];
            const float4 nj = ndj[node];
            f = ni.x; zr = ni.y; zi = ni.z;
            wr = nj.y; wi = -nj.z;
        }
        float p[16] = { f, f*f, zr, zi, wr, wi, f*zr, f*zi, f*wr, f*wi,
                        zr*zr, zi*zi, zr*zi, wr*wr, wi*wi, wr*wi };
#pragma unroll
        for (int k = 0; k < 16; ++k) {
            float v = p[k];
#pragma unroll
            for (int off = 32; off > 0; off >>= 1) v += __shfl_down(v, off, 64);
            p[k] = v;
        }
        if (lane == 0) {
            const double P0 = p[0], P1 = p[1], P2 = p[2], P3 = p[3], P4 = p[4];
            const double P5 = p[5], P6 = p[6], P7 = p[7], P8 = p[8], P9 = p[9];
            const double P10 = p[10], P11 = p[11], P12 = p[12];
            const double P13 = p[13], P14 = p[14], P15 = p[15];
            const double Sfi = 50.0 * P0;
            const double Sdr = P2*P4 - P3*P5;
            const double Sdi = P3*P4 + P2*P5;
            const double m00 = 50.0 * P1, m11 = m00, m01 = P0*P0;
            const double m02 = P6*P4 - P7*P5;
            const double m03 = P7*P4 + P6*P5;
            const double m12 = P2*P8 - P3*P9;
            const double m13 = P3*P8 + P2*P9;
            const double m22 = P10*P13 - 2.0*P12*P15 + P11*P14;
            const double m33 = P11*P13 + 2.0*P12*P15 + P10*P14;
            const double m23 = P12*P13 + P10*P15 - P11*P15 - P12*P14;
#pragma unroll
            for (int o = 0; o < 5; ++o) {
                const double a0=v0[o], a1=v1[o], a2=v2[o], a3=v3[o], bo=bb1[o];
                const double sy = a0*Sfi + a1*Sfi + a2*Sdr + a3*Sdi + 2500.0*bo;
                const double q  = a0*a0*m00 + a1*a1*m11 + a2*a2*m22 + a3*a3*m33
                               + 2.0*(a0*a1*m01 + a0*a2*m02 + a0*a3*m03
                                    + a1*a2*m12 + a1*a3*m13 + a2*a3*m23);
                bacc[wv][o]   = sy;
                bacc[wv][5+o] = q + 2.0*bo*sy - 2500.0*bo*bo;
            }
        }
    }
    __syncthreads();

    if (t < 10) {
        double s = bacc[0][t] + bacc[1][t];
        atomicAdd(&acc[t * NCOPY + (blockIdx.x & (NCOPY-1))], s);
    }

    gbar(&bar[0]);   // all phase-A atomics complete & visible

    // ==== phase B: fold BN1 into L1; sweep edges for S=sum h1, M=sum h1 h1^T
    if (t < 10) {
        double s = 0.0;
#pragma unroll
        for (int c = 0; c < NCOPY; ++c) s += aload(&acc[t * NCOPY + c]);
        tmp[t] = s;
    }
    __syncthreads();

#pragma unroll
    for (int o = 0; o < 5; ++o) {
        double mu  = tmp[o]   * INV_ETOT;
        double var = tmp[5+o] * INV_ETOT - mu * mu;
        float sc = rfl(g1[o]) * rsqrtf((float)var + EPSF);
        float sh = rfl(rfl(bt1[o]) - (float)mu * sc);
        v0[o] = rfl(v0[o] * sc);
        v1[o] = rfl(v1[o] * sc);
        v2[o] = rfl(v2[o] * sc);
        v3[o] = rfl(v3[o] * sc);
        bb1[o] = rfl(fmaf(bb1[o], sc, sh));
    }

    const int pi = t / 5;
    const int s5 = t - pi * 5;

    {
        float s1[5] = {0.f, 0.f, 0.f, 0.f, 0.f};
        float mm[15];
#pragma unroll
        for (int k = 0; k < 15; ++k) mm[k] = 0.f;

        if (t < 250) {
#pragma unroll
            for (int g = 0; g < GBF; ++g) {
                const float4 ni = nd[g*PP + pi];
                const float fi = ni.x, ari = ni.y, aii = ni.z;
                float4 njs[10];
#pragma unroll
                for (int q = 0; q < 10; ++q) njs[q] = ndj[g*PP + s5*10 + q];
#pragma unroll
                for (int q = 0; q < 10; ++q) {
                    const float4 nj = njs[q];
                    const float dr = fmaf(ari, nj.y,  aii*nj.z);
                    const float di = fmaf(aii, nj.y, -ari*nj.z);
                    float h1[5];
#pragma unroll
                    for (int o = 0; o < 5; ++o) {
                        float y = fmaf(v0[o], fi, fmaf(v1[o], nj.x,
                                  fmaf(v2[o], dr, fmaf(v3[o], di, bb1[o]))));
                        h1[o] = lrelu(y);
                    }
#pragma unroll
                    for (int k = 0; k < 5; ++k) {
                        s1[k] += h1[k];
#pragma unroll
                        for (int l = k; l < 5; ++l) {
                            const int idx = k*5 - (k*(k+1))/2 + l;
                            mm[idx] = fmaf(h1[k], h1[l], mm[idx]);
                        }
                    }
                }
            }
        }

        float a[20];
#pragma unroll
        for (int k = 0; k < 5; ++k) a[k] = s1[k];
#pragma unroll
        for (int k = 0; k < 15; ++k) a[5+k] = mm[k];
#pragma unroll
        for (int k = 0; k < 20; ++k) {
            float v = a[k];
#pragma unroll
            for (int off = 32; off > 0; off >>= 1) v += __shfl_down(v, off, 64);
            a[k] = v;
        }
        if (lane == 0) {
#pragma unroll
            for (int k = 0; k < 20; ++k) red[wv][k] = a[k];
        }
    }
    __syncthreads();
    if (t < 20) {
        atomicAdd(&acc[(10 + t) * NCOPY + (blockIdx.x & (NCOPY-1))],
                  (double)(red[0][t] + red[1][t] + red[2][t] + red[3][t]));
    }

    gbar(&bar[256]);   // all phase-B atomics complete & visible

    // ==== phase C: BN2 from moments, fold, full MLP sweep, aggregate, write
    if (t < 20) {
        double s = 0.0;
#pragma unroll
        for (int c = 0; c < NCOPY; ++c) s += aload(&acc[(10 + t) * NCOPY + c]);
        tmp[10 + t] = s;
    }

    float w2[25], bb2[5];
#pragma unroll
    for (int i = 0; i < 25; ++i) w2[i] = rfl(W2[i]);
#pragma unroll
    for (int o = 0; o < 5; ++o) bb2[o] = rfl(b2[o]);
    __syncthreads();

    // mu2[o] = w_o.Sn + b2[o];  var2[o] = w_o^T Mn w_o - (w_o.Sn)^2  (b2 cancels)
    if (t < 5) {
        const int o = t;
        double w[5], Sn[5];
#pragma unroll
        for (int k = 0; k < 5; ++k) {
            w[k]  = (double)w2[o*5+k];
            Sn[k] = tmp[10+k] * INV_ETOT;
        }
        double muw = 0.0;
#pragma unroll
        for (int k = 0; k < 5; ++k) muw += w[k] * Sn[k];
        double q = 0.0;
#pragma unroll
        for (int k = 0; k < 5; ++k) {
#pragma unroll
            for (int l = k; l < 5; ++l) {
                const int idx = k*5 - (k*(k+1))/2 + l;
                const double Mn = tmp[15+idx] * INV_ETOT;
                q += (k == l ? w[k]*w[k] : 2.0*w[k]*w[l]) * Mn;
            }
        }
        double var2 = q - muw * muw;
        double mu2  = muw + (double)bb2[o];
        float sc2 = g2[o] * rsqrtf((float)var2 + EPSF);
        scsh[0][o] = sc2;
        scsh[1][o] = bt2[o] - (float)mu2 * sc2;
    }
    __syncthreads();

#pragma unroll
    for (int o = 0; o < 5; ++o) {
        const float s2f = rfl(scsh[0][o]);
        const float s2h = rfl(scsh[1][o]);
#pragma unroll
        for (int k = 0; k < 5; ++k) w2[o*5+k] = rfl(w2[o*5+k] * s2f);
        bb2[o] = rfl(fmaf(bb2[o], s2f, s2h));
    }

    float w3[25], bb3[5];
#pragma unroll
    for (int i = 0; i < 25; ++i) w3[i] = rfl(W3[i]);
#pragma unroll
    for (int o = 0; o < 5; ++o) bb3[o] = rfl(b3[o]);

#pragma unroll
    for (int g = 0; g < GBF; ++g) {
        float a[5] = {0.f, 0.f, 0.f, 0.f, 0.f};
        if (t < 250) {
            const float4 ni = nd[g*PP + pi];
            const float fi = ni.x, ari = ni.y, aii = ni.z;
            float4 njs[10];
#pragma unroll
            for (int q = 0; q < 10; ++q) njs[q] = ndj[g*PP + s5*10 + q];
#pragma unroll
            for (int q = 0; q < 10; ++q) {
                const float4 nj = njs[q];
                const float dr = fmaf(ari, nj.y,  aii*nj.z);
                const float di = fmaf(aii, nj.y, -ari*nj.z);
                float h1[5], h2[5];
#pragma unroll
                for (int o = 0; o < 5; ++o) {
                    float y = fmaf(v0[o], fi, fmaf(v1[o], nj.x,
                              fmaf(v2[o], dr, fmaf(v3[o], di, bb1[o]))));
                    h1[o] = lrelu(y);
                }
#pragma unroll
                for (int o = 0; o < 5; ++o) {
                    float y = bb2[o];
                    y = fmaf(w2[o*5+0], h1[0], y);
                    y = fmaf(w2[o*5+1], h1[1], y);
                    y = fmaf(w2[o*5+2], h1[2], y);
                    y = fmaf(w2[o*5+3], h1[3], y);
                    y = fmaf(w2[o*5+4], h1[4], y);
                    h2[o] = lrelu(y);
                }
#pragma unroll
                for (int o = 0; o < 5; ++o) a[o] += h2[o];
            }
#pragma unroll
            for (int c = 0; c < 5; ++c) part[t][c] = a[c];
        }
        __syncthreads();

        if (t < PP) {
            float hm[5];
#pragma unroll
            for (int c = 0; c < 5; ++c) {
                hm[c] = (part[5*t][c] + part[5*t+1][c] + part[5*t+2][c] +
                         part[5*t+3][c] + part[5*t+4][c]) * 0.02f;
            }
            // layer 3 hoisted: mean commutes with affine W3
            float m[5];
#pragma unroll
            for (int c = 0; c < 5; ++c) {
                float y = bb3[c];
                y = fmaf(w3[c*5+0], hm[0], y);
                y = fmaf(w3[c*5+1], hm[1], y);
                y = fmaf(w3[c*5+2], hm[2], y);
                y = fmaf(w3[c*5+3], hm[3], y);
                y = fmaf(w3[c*5+4], hm[4], y);
                m[c] = y;
            }
            const int node = g*PP + t;
            const int d = blockIdx.x * (GBF * PP) + node;
            const float4 ni = nd[node];
            float ss, cc;
            sincosf(6.2831853071795865f * m[4], &ss, &cc);
            float* o = out + (size_t)d * 7;
            o[0] = spt[node];
            o[1] = m[0];
            o[2] = m[1];
            o[3] = m[2];
            o[4] = m[3];
            o[5] = cc * ni.y - ss * ni.z;
            o[6] = cc * ni.z + ss * ni.y;
        }
        __syncthreads();
    }
}

extern "C" void kernel_launch(void* const* d_in, const int* in_sizes, int n_in,
                              void* d_out, int out_size, void* d_ws, size_t ws_size,
                              hipStream_t stream)
{
    const float* pt   = (const float*)d_in[0];
    const float* feat = (const float*)d_in[1];
    const float* ang  = (const float*)d_in[2];
    const float* W1   = (const float*)d_in[3];
    const float* b1   = (const float*)d_in[4];
    const float* g1   = (const float*)d_in[5];
    const float* bt1  = (const float*)d_in[6];
    const float* W2   = (const float*)d_in[7];
    const float* b2   = (const float*)d_in[8];
    const float* g2   = (const float*)d_in[9];
    const float* bt2  = (const float*)d_in[10];
    const float* W3   = (const float*)d_in[11];
    const float* b3   = (const float*)d_in[12];
    // d_in[13] = edge_index: closed-form structure (dst=b*P+pi, src=b*P+pj), unused
    float* out = (float*)d_out;
    double* acc = (double*)d_ws;                         // NSLOT*NCOPY doubles
    unsigned* bar = (unsigned*)(acc + NSLOT * NCOPY);    // 2 barrier zones x 256 u32

    hipMemsetAsync(d_ws, 0,
                   NSLOT * NCOPY * sizeof(double) + 512 * sizeof(unsigned),
                   stream);
    fused_kernel<<<NBLKF, TPB, 0, stream>>>(pt, feat, ang, W1, b1, g1, bt1,
                                            W2, b2, g2, bt2, W3, b3,
                                            acc, bar, out);
}

// Round 5
// 152.152 us; speedup vs baseline: 1.5832x; 1.5832x over previous
//
#include <hip/hip_runtime.h>

#define PP 50
#define TPB 256
#define NBATCH 2048
#define GB 2                     // batches per block in edge-sweep kernels
#define NBLK2 (NBATCH / GB)      // 1024 blocks for K2/K3
#define NBLK1 512                // K1: 4 batches/block, 1 wave each
#define NCOPY 32                 // contention-spreading copies for K2 stat atomics
// d_ws layout (doubles):
//   acc[0 .. 20*NCOPY)          : K2->K3 moment atomics (zeroed by K1 block 0)
//   pacc[0 .. 10*NBLK1)         : K1 per-block BN1 partials (plain stores)

static constexpr float EPSF = 1e-5f;
static constexpr double INV_ETOT = 1.0 / 5120000.0;   // 1/(B*P*P)

static __device__ __forceinline__ float lrelu(float x) {
    return fmaxf(x, 0.01f * x);
}
static __device__ __forceinline__ float rfl(float x) {
    return __int_as_float(__builtin_amdgcn_readfirstlane(__float_as_int(x)));
}

// ==== K1: BN1 stats via separable per-node sums; per-block partial stores ===
__global__ __launch_bounds__(TPB) void stats1_kernel(
    const float* __restrict__ feat, const float* __restrict__ ang,
    const float* __restrict__ W1, const float* __restrict__ b1,
    double* __restrict__ acc, double* __restrict__ pacc)
{
    __shared__ double bacc[4][10];
    const int t = threadIdx.x;
    const int lane = t & 63;
    const int wv = t >> 6;

    // block 0 zeroes K2's atomic slots (K1 completes before K2 starts)
    if (blockIdx.x == 0) {
        for (int i = t; i < 20 * NCOPY; i += TPB) acc[i] = 0.0;
    }

    float v0[5], v1[5], v2[5], v3[5], bb1[5];
#pragma unroll
    for (int o = 0; o < 5; ++o) {
        v0[o] = rfl(W1[o*5+0] - W1[o*5+2]);
        v1[o] = rfl(W1[o*5+1] + W1[o*5+2]);
        v2[o] = rfl(W1[o*5+3]);
        v3[o] = rfl(W1[o*5+4]);
        bb1[o] = rfl(b1[o]);
    }

    float f = 0.f, zr = 0.f, zi = 0.f, inv = 0.f;
    if (lane < PP) {
        const int idx = (blockIdx.x * 4 + wv) * PP + lane;
        f = feat[idx];
        float2 a2 = ((const float2*)ang)[idx];
        zr = a2.x; zi = a2.y;
        inv = 1.0f / (zr*zr + zi*zi);
    }
    const float wr = zr * inv, wi = -zi * inv;   // lanes >=50: all zero

    float p[16] = { f, f*f, zr, zi, wr, wi, f*zr, f*zi, f*wr, f*wi,
                    zr*zr, zi*zi, zr*zi, wr*wr, wi*wi, wr*wi };
#pragma unroll
    for (int k = 0; k < 16; ++k) {
        float v = p[k];
#pragma unroll
        for (int off = 32; off > 0; off >>= 1) v += __shfl_down(v, off, 64);
        p[k] = v;
    }
    if (lane == 0) {
        const double P0 = p[0], P1 = p[1], P2 = p[2], P3 = p[3], P4 = p[4];
        const double P5 = p[5], P6 = p[6], P7 = p[7], P8 = p[8], P9 = p[9];
        const double P10 = p[10], P11 = p[11], P12 = p[12];
        const double P13 = p[13], P14 = p[14], P15 = p[15];
        const double Sfi = 50.0 * P0;
        const double Sdr = P2*P4 - P3*P5;
        const double Sdi = P3*P4 + P2*P5;
        const double m00 = 50.0 * P1, m11 = m00, m01 = P0*P0;
        const double m02 = P6*P4 - P7*P5;
        const double m03 = P7*P4 + P6*P5;
        const double m12 = P2*P8 - P3*P9;
        const double m13 = P3*P8 + P2*P9;
        const double m22 = P10*P13 - 2.0*P12*P15 + P11*P14;
        const double m33 = P11*P13 + 2.0*P12*P15 + P10*P14;
        const double m23 = P12*P13 + P10*P15 - P11*P15 - P12*P14;
#pragma unroll
        for (int o = 0; o < 5; ++o) {
            const double a0=v0[o], a1=v1[o], a2=v2[o], a3=v3[o], bo=bb1[o];
            const double sy = a0*Sfi + a1*Sfi + a2*Sdr + a3*Sdi + 2500.0*bo;
            const double q  = a0*a0*m00 + a1*a1*m11 + a2*a2*m22 + a3*a3*m33
                           + 2.0*(a0*a1*m01 + a0*a2*m02 + a0*a3*m03
                                + a1*a2*m12 + a1*a3*m13 + a2*a3*m23);
            bacc[wv][o]   = sy;
            bacc[wv][5+o] = q + 2.0*bo*sy - 2500.0*bo*bo;
        }
    }
    __syncthreads();
    if (t < 10) {
        pacc[t * NBLK1 + blockIdx.x] =
            bacc[0][t] + bacc[1][t] + bacc[2][t] + bacc[3][t];
    }
}

// ==== K2: fold BN1; edge sweep for S=sum h1, M=sum h1 h1^T ================
__global__ __launch_bounds__(TPB, 2) void pass2_kernel(
    const float* __restrict__ feat, const float* __restrict__ ang,
    const float* __restrict__ W1, const float* __restrict__ b1,
    const float* __restrict__ g1, const float* __restrict__ bt1,
    double* __restrict__ acc, const double* __restrict__ pacc)
{
    __shared__ float4 nd[GB * PP];    // (f, ar, ai, -)            i-side
    __shared__ float4 ndj[GB * PP];   // (f, ar/|a|2, ai/|a|2, -)  j-side
    __shared__ double tmp[10];
    __shared__ double pred[10][16];
    __shared__ float red[4][20];
    const int t = threadIdx.x;

    if (t < GB * PP) {
        const int idx = blockIdx.x * (GB * PP) + t;
        float f = feat[idx];
        float2 a2 = ((const float2*)ang)[idx];
        float inv = 1.0f / (a2.x*a2.x + a2.y*a2.y);
        nd[t]  = make_float4(f, a2.x, a2.y, 0.0f);
        ndj[t] = make_float4(f, a2.x * inv, a2.y * inv, 0.0f);
    } else if (t >= 100 && t < 250) {
        const int r = t - 100;
        const int slot = r / 15, sub = r - slot * 15;
        double s = 0.0;
        for (int b = sub; b < NBLK1; b += 15) s += pacc[slot * NBLK1 + b];
        pred[slot][sub] = s;
    }

    float v0[5], v1[5], v2[5], v3[5], bb1[5];
#pragma unroll
    for (int o = 0; o < 5; ++o) {
        v0[o] = rfl(W1[o*5+0] - W1[o*5+2]);
        v1[o] = rfl(W1[o*5+1] + W1[o*5+2]);
        v2[o] = rfl(W1[o*5+3]);
        v3[o] = rfl(W1[o*5+4]);
        bb1[o] = rfl(b1[o]);
    }

    __syncthreads();
    if (t < 10) {
        double s = 0.0;
#pragma unroll
        for (int k = 0; k < 15; ++k) s += pred[t][k];
        tmp[t] = s;
    }
    __syncthreads();

    // BN1 folded into layer-1 weights: v' = sc1*v, b' = sc1*b1 + sh1
#pragma unroll
    for (int o = 0; o < 5; ++o) {
        double mu  = tmp[o]   * INV_ETOT;
        double var = tmp[5+o] * INV_ETOT - mu * mu;
        float sc = rfl(g1[o]) * rsqrtf((float)var + EPSF);
        float sh = rfl(rfl(bt1[o]) - (float)mu * sc);
        v0[o] = rfl(v0[o] * sc);
        v1[o] = rfl(v1[o] * sc);
        v2[o] = rfl(v2[o] * sc);
        v3[o] = rfl(v3[o] * sc);
        bb1[o] = rfl(fmaf(bb1[o], sc, sh));
    }

    float s1[5] = {0.f, 0.f, 0.f, 0.f, 0.f};
    float mm[15];
#pragma unroll
    for (int k = 0; k < 15; ++k) mm[k] = 0.f;

    if (t < 250) {
        const int pi = t / 5;
        const int s5 = t - pi*5;
#pragma unroll
        for (int g = 0; g < GB; ++g) {
            const float4 ni = nd[g*PP + pi];
            const float fi = ni.x, ari = ni.y, aii = ni.z;
            float4 njs[10];
#pragma unroll
            for (int q = 0; q < 10; ++q) njs[q] = ndj[g*PP + s5*10 + q];
#pragma unroll
            for (int q = 0; q < 10; ++q) {
                const float4 nj = njs[q];
                const float dr = fmaf(ari, nj.y,  aii*nj.z);
                const float di = fmaf(aii, nj.y, -ari*nj.z);
                float h1[5];
#pragma unroll
                for (int o = 0; o < 5; ++o) {
                    float y = fmaf(v0[o], fi, fmaf(v1[o], nj.x,
                              fmaf(v2[o], dr, fmaf(v3[o], di, bb1[o]))));
                    h1[o] = lrelu(y);
                }
#pragma unroll
                for (int k = 0; k < 5; ++k) {
                    s1[k] += h1[k];
#pragma unroll
                    for (int l = k; l < 5; ++l) {
                        const int idx = k*5 - (k*(k+1))/2 + l;
                        mm[idx] = fmaf(h1[k], h1[l], mm[idx]);
                    }
                }
            }
        }
    }

    float a[20];
#pragma unroll
    for (int k = 0; k < 5; ++k) a[k] = s1[k];
#pragma unroll
    for (int k = 0; k < 15; ++k) a[5+k] = mm[k];
#pragma unroll
    for (int k = 0; k < 20; ++k) {
        float v = a[k];
#pragma unroll
        for (int off = 32; off > 0; off >>= 1) v += __shfl_down(v, off, 64);
        a[k] = v;
    }
    const int lane = t & 63, wv = t >> 6;
    if (lane == 0) {
#pragma unroll
        for (int k = 0; k < 20; ++k) red[wv][k] = a[k];
    }
    __syncthreads();
    if (t < 20) {
        atomicAdd(&acc[t * NCOPY + (blockIdx.x & (NCOPY-1))],
                  (double)(red[0][t] + red[1][t] + red[2][t] + red[3][t]));
    }
}

// ==== K3: full MLP (BN folded, L3 hoisted), aggregate, rotate, write =======
__global__ __launch_bounds__(TPB, 2) void pass3_kernel(
    const float* __restrict__ pt,
    const float* __restrict__ feat, const float* __restrict__ ang,
    const float* __restrict__ W1, const float* __restrict__ b1,
    const float* __restrict__ g1, const float* __restrict__ bt1,
    const float* __restrict__ W2, const float* __restrict__ b2,
    const float* __restrict__ g2, const float* __restrict__ bt2,
    const float* __restrict__ W3, const float* __restrict__ b3,
    const double* __restrict__ acc, const double* __restrict__ pacc,
    float* __restrict__ out)
{
    __shared__ float4 nd[GB * PP];
    __shared__ float4 ndj[GB * PP];
    __shared__ float spt[GB * PP];
    __shared__ double tmp[30];
    __shared__ double pred[10][16];
    __shared__ float scsh[2][5];      // sc2, sh2
    __shared__ float part[250][5];
    __shared__ __align__(16) float ob[PP * 7 + 2];   // coalesced-write staging
    const int t = threadIdx.x;

    if (t < GB * PP) {
        const int idx = blockIdx.x * (GB * PP) + t;
        float f = feat[idx];
        float2 a2 = ((const float2*)ang)[idx];
        float inv = 1.0f / (a2.x*a2.x + a2.y*a2.y);
        nd[t]  = make_float4(f, a2.x, a2.y, 0.0f);
        ndj[t] = make_float4(f, a2.x * inv, a2.y * inv, 0.0f);
        spt[t] = pt[idx];
    }
    if (t < 20) {
        double s = 0.0;
#pragma unroll
        for (int c = 0; c < NCOPY; ++c) s += acc[t * NCOPY + c];
        tmp[10 + t] = s;
    } else if (t >= 100 && t < 250) {
        const int r = t - 100;
        const int slot = r / 15, sub = r - slot * 15;
        double s = 0.0;
        for (int b = sub; b < NBLK1; b += 15) s += pacc[slot * NBLK1 + b];
        pred[slot][sub] = s;
    }

    float v0[5], v1[5], v2[5], v3[5], bb1[5], w2[25], bb2[5], w3[25], bb3[5];
#pragma unroll
    for (int o = 0; o < 5; ++o) {
        v0[o] = rfl(W1[o*5+0] - W1[o*5+2]);
        v1[o] = rfl(W1[o*5+1] + W1[o*5+2]);
        v2[o] = rfl(W1[o*5+3]);
        v3[o] = rfl(W1[o*5+4]);
        bb1[o] = rfl(b1[o]); bb2[o] = rfl(b2[o]); bb3[o] = rfl(b3[o]);
    }
#pragma unroll
    for (int i = 0; i < 25; ++i) { w2[i] = rfl(W2[i]); w3[i] = rfl(W3[i]); }

    __syncthreads();
    if (t < 10) {
        double s = 0.0;
#pragma unroll
        for (int k = 0; k < 15; ++k) s += pred[t][k];
        tmp[t] = s;
    }
    __syncthreads();

    // fold BN1 into layer 1
#pragma unroll
    for (int o = 0; o < 5; ++o) {
        double mu  = tmp[o]   * INV_ETOT;
        double var = tmp[5+o] * INV_ETOT - mu * mu;
        float sc = rfl(g1[o]) * rsqrtf((float)var + EPSF);
        float sh = rfl(rfl(bt1[o]) - (float)mu * sc);
        v0[o] = rfl(v0[o] * sc);
        v1[o] = rfl(v1[o] * sc);
        v2[o] = rfl(v2[o] * sc);
        v3[o] = rfl(v3[o] * sc);
        bb1[o] = rfl(fmaf(bb1[o], sc, sh));
    }

    // BN2 from moments: mu2 = w_o.Sn + b2[o]; var2 = w_o^T Mn w_o - (w_o.Sn)^2
    if (t < 5) {
        const int o = t;
        double w[5], Sn[5];
#pragma unroll
        for (int k = 0; k < 5; ++k) {
            w[k]  = (double)w2[o*5+k];
            Sn[k] = tmp[10+k] * INV_ETOT;
        }
        double muw = 0.0;
#pragma unroll
        for (int k = 0; k < 5; ++k) muw += w[k] * Sn[k];
        double q = 0.0;
#pragma unroll
        for (int k = 0; k < 5; ++k) {
#pragma unroll
            for (int l = k; l < 5; ++l) {
                const int idx = k*5 - (k*(k+1))/2 + l;
                const double Mn = tmp[15+idx] * INV_ETOT;
                q += (k == l ? w[k]*w[k] : 2.0*w[k]*w[l]) * Mn;
            }
        }
        double var2 = q - muw * muw;
        double mu2  = muw + (double)bb2[o];
        float sc2 = g2[o] * rsqrtf((float)var2 + EPSF);
        scsh[0][o] = sc2;
        scsh[1][o] = bt2[o] - (float)mu2 * sc2;
    }
    __syncthreads();

#pragma unroll
    for (int o = 0; o < 5; ++o) {
        const float s2f = rfl(scsh[0][o]);
        const float s2h = rfl(scsh[1][o]);
#pragma unroll
        for (int k = 0; k < 5; ++k) w2[o*5+k] = rfl(w2[o*5+k] * s2f);
        bb2[o] = rfl(fmaf(bb2[o], s2f, s2h));
    }

    const int pi = t / 5;
    const int s5 = t - pi*5;

#pragma unroll
    for (int g = 0; g < GB; ++g) {
        float a[5] = {0.f, 0.f, 0.f, 0.f, 0.f};
        if (t < 250) {
            const float4 ni = nd[g*PP + pi];
            const float fi = ni.x, ari = ni.y, aii = ni.z;
            float4 njs[10];
#pragma unroll
            for (int q = 0; q < 10; ++q) njs[q] = ndj[g*PP + s5*10 + q];
#pragma unroll
            for (int q = 0; q < 10; ++q) {
                const float4 nj = njs[q];
                const float dr = fmaf(ari, nj.y,  aii*nj.z);
                const float di = fmaf(aii, nj.y, -ari*nj.z);
                float h1[5], h2[5];
#pragma unroll
                for (int o = 0; o < 5; ++o) {
                    float y = fmaf(v0[o], fi, fmaf(v1[o], nj.x,
                              fmaf(v2[o], dr, fmaf(v3[o], di, bb1[o]))));
                    h1[o] = lrelu(y);
                }
#pragma unroll
                for (int o = 0; o < 5; ++o) {
                    float y = bb2[o];
                    y = fmaf(w2[o*5+0], h1[0], y);
                    y = fmaf(w2[o*5+1], h1[1], y);
                    y = fmaf(w2[o*5+2], h1[2], y);
                    y = fmaf(w2[o*5+3], h1[3], y);
                    y = fmaf(w2[o*5+4], h1[4], y);
                    h2[o] = lrelu(y);
                }
#pragma unroll
                for (int o = 0; o < 5; ++o) a[o] += h2[o];
            }
#pragma unroll
            for (int c = 0; c < 5; ++c) part[t][c] = a[c];
        }
        __syncthreads();

        if (t < PP) {
            float hm[5];
#pragma unroll
            for (int c = 0; c < 5; ++c) {
                hm[c] = (part[5*t][c] + part[5*t+1][c] + part[5*t+2][c] +
                         part[5*t+3][c] + part[5*t+4][c]) * 0.02f;
            }
            // layer 3 hoisted: mean commutes with affine W3
            float m[5];
#pragma unroll
            for (int c = 0; c < 5; ++c) {
                float y = bb3[c];
                y = fmaf(w3[c*5+0], hm[0], y);
                y = fmaf(w3[c*5+1], hm[1], y);
                y = fmaf(w3[c*5+2], hm[2], y);
                y = fmaf(w3[c*5+3], hm[3], y);
                y = fmaf(w3[c*5+4], hm[4], y);
                m[c] = y;
            }
            const int node = g*PP + t;
            const float4 ni = nd[node];
            float ss, cc;
            sincosf(6.2831853071795865f * m[4], &ss, &cc);
            float* o = &ob[t * 7];
            o[0] = spt[node];
            o[1] = m[0];
            o[2] = m[1];
            o[3] = m[2];
            o[4] = m[3];
            o[5] = cc * ni.y - ss * ni.z;
            o[6] = cc * ni.z + ss * ni.y;
        }
        __syncthreads();

        if (t < 175) {   // 350 floats = 175 float2, 8B-aligned coalesced write
            float2* dst = (float2*)(out +
                (size_t)(blockIdx.x * (GB * PP) + g * PP) * 7);
            dst[t] = ((const float2*)ob)[t];
        }
        __syncthreads();
    }
}

extern "C" void kernel_launch(void* const* d_in, const int* in_sizes, int n_in,
                              void* d_out, int out_size, void* d_ws, size_t ws_size,
                              hipStream_t stream)
{
    const float* pt   = (const float*)d_in[0];
    const float* feat = (const float*)d_in[1];
    const float* ang  = (const float*)d_in[2];
    const float* W1   = (const float*)d_in[3];
    const float* b1   = (const float*)d_in[4];
    const float* g1   = (const float*)d_in[5];
    const float* bt1  = (const float*)d_in[6];
    const float* W2   = (const float*)d_in[7];
    const float* b2   = (const float*)d_in[8];
    const float* g2   = (const float*)d_in[9];
    const float* bt2  = (const float*)d_in[10];
    const float* W3   = (const float*)d_in[11];
    const float* b3   = (const float*)d_in[12];
    // d_in[13] = edge_index: closed-form structure (dst=b*P+pi, src=b*P+pj), unused
    float* out = (float*)d_out;
    double* acc  = (double*)d_ws;            // 20*NCOPY doubles (K1 blk0 zeroes)
    double* pacc = acc + 20 * NCOPY;         // 10*NBLK1 doubles (plain stores)

    stats1_kernel<<<NBLK1, TPB, 0, stream>>>(feat, ang, W1, b1, acc, pacc);
    pass2_kernel<<<NBLK2, TPB, 0, stream>>>(feat, ang, W1, b1, g1, bt1, acc, pacc);
    pass3_kernel<<<NBLK2, TPB, 0, stream>>>(pt, feat, ang, W1, b1, g1, bt1,
                                            W2, b2, g2, bt2, W3, b3,
                                            acc, pacc, out);
}

// Round 6
// 138.058 us; speedup vs baseline: 1.7448x; 1.1021x over previous
//
#include <hip/hip_runtime.h>

#define PP 50
#define TPB 1024                 // 16 waves/block = 4 waves/SIMD at 1 block/CU
#define NBATCH 2048
#define GBK 16                   // K1: batches per block (one per wave)
#define NBLK1 (NBATCH / GBK)     // 128 blocks
#define GB 8                     // K2/K3: batches per block
#define NBLK2 (NBATCH / GB)      // 256 blocks = exactly 1 per CU
#define NCOPY 32                 // contention-spreading copies for K2 stat atomics
// d_ws layout (doubles):
//   acc[0 .. 20*NCOPY)   : K2->K3 moment atomic slots (zeroed by K1 block 0)
//   pacc[0 .. 10*NBLK1)  : K1 per-block BN1 partials (plain stores, layout [slot][128])

static constexpr float EPSF = 1e-5f;
static constexpr double INV_ETOT = 1.0 / 5120000.0;   // 1/(B*P*P)

static __device__ __forceinline__ float lrelu(float x) {
    return fmaxf(x, 0.01f * x);
}
static __device__ __forceinline__ float rfl(float x) {
    return __int_as_float(__builtin_amdgcn_readfirstlane(__float_as_int(x)));
}

// ==== K1: BN1 stats via separable per-node sums; per-block partial stores ===
__global__ __launch_bounds__(TPB) void stats1_kernel(
    const float* __restrict__ feat, const float* __restrict__ ang,
    const float* __restrict__ W1, const float* __restrict__ b1,
    double* __restrict__ acc, double* __restrict__ pacc)
{
    __shared__ double bacc[GBK][10];
    const int t = threadIdx.x;
    const int lane = t & 63;
    const int wv = t >> 6;       // wave = batch within block, [0,16)

    // block 0 zeroes K2's atomic slots (K1 fully completes before K2 starts)
    if (blockIdx.x == 0 && t < 20 * NCOPY) acc[t] = 0.0;

    float v0[5], v1[5], v2[5], v3[5], bb1[5];
#pragma unroll
    for (int o = 0; o < 5; ++o) {
        v0[o] = rfl(W1[o*5+0] - W1[o*5+2]);
        v1[o] = rfl(W1[o*5+1] + W1[o*5+2]);
        v2[o] = rfl(W1[o*5+3]);
        v3[o] = rfl(W1[o*5+4]);
        bb1[o] = rfl(b1[o]);
    }

    float f = 0.f, zr = 0.f, zi = 0.f, inv = 0.f;
    if (lane < PP) {
        const int idx = (blockIdx.x * GBK + wv) * PP + lane;
        f = feat[idx];
        float2 a2 = ((const float2*)ang)[idx];
        zr = a2.x; zi = a2.y;
        inv = 1.0f / (zr*zr + zi*zi);
    }
    const float wr = zr * inv, wi = -zi * inv;   // lanes >=50: all zero

    float p[16] = { f, f*f, zr, zi, wr, wi, f*zr, f*zi, f*wr, f*wi,
                    zr*zr, zi*zi, zr*zi, wr*wr, wi*wi, wr*wi };
#pragma unroll
    for (int k = 0; k < 16; ++k) {
        float v = p[k];
#pragma unroll
        for (int off = 32; off > 0; off >>= 1) v += __shfl_down(v, off, 64);
        p[k] = v;
    }
    if (lane == 0) {
        const double P0 = p[0], P1 = p[1], P2 = p[2], P3 = p[3], P4 = p[4];
        const double P5 = p[5], P6 = p[6], P7 = p[7], P8 = p[8], P9 = p[9];
        const double P10 = p[10], P11 = p[11], P12 = p[12];
        const double P13 = p[13], P14 = p[14], P15 = p[15];
        const double Sfi = 50.0 * P0;
        const double Sdr = P2*P4 - P3*P5;
        const double Sdi = P3*P4 + P2*P5;
        const double m00 = 50.0 * P1, m11 = m00, m01 = P0*P0;
        const double m02 = P6*P4 - P7*P5;
        const double m03 = P7*P4 + P6*P5;
        const double m12 = P2*P8 - P3*P9;
        const double m13 = P3*P8 + P2*P9;
        const double m22 = P10*P13 - 2.0*P12*P15 + P11*P14;
        const double m33 = P11*P13 + 2.0*P12*P15 + P10*P14;
        const double m23 = P12*P13 + P10*P15 - P11*P15 - P12*P14;
#pragma unroll
        for (int o = 0; o < 5; ++o) {
            const double a0=v0[o], a1=v1[o], a2=v2[o], a3=v3[o], bo=bb1[o];
            const double sy = a0*Sfi + a1*Sfi + a2*Sdr + a3*Sdi + 2500.0*bo;
            const double q  = a0*a0*m00 + a1*a1*m11 + a2*a2*m22 + a3*a3*m33
                           + 2.0*(a0*a1*m01 + a0*a2*m02 + a0*a3*m03
                                + a1*a2*m12 + a1*a3*m13 + a2*a3*m23);
            bacc[wv][o]   = sy;
            bacc[wv][5+o] = q + 2.0*bo*sy - 2500.0*bo*bo;
        }
    }
    __syncthreads();
    if (t < 10) {
        double s = 0.0;
#pragma unroll
        for (int w = 0; w < GBK; ++w) s += bacc[w][t];
        pacc[t * NBLK1 + blockIdx.x] = s;
    }
}

// ==== K2: fold BN1; edge sweep for S=sum h1, M=sum h1 h1^T ================
__global__ __launch_bounds__(TPB) void pass2_kernel(
    const float* __restrict__ feat, const float* __restrict__ ang,
    const float* __restrict__ W1, const float* __restrict__ b1,
    const float* __restrict__ g1, const float* __restrict__ bt1,
    double* __restrict__ acc, const double* __restrict__ pacc)
{
    __shared__ float4 nd[GB * PP];    // (f, ar, ai, -)            i-side
    __shared__ float4 ndj[GB * PP];   // (f, ar/|a|2, ai/|a|2, -)  j-side
    __shared__ double predl[10][32];
    __shared__ double tmp[10];
    __shared__ float red[16][20];
    const int t = threadIdx.x;

    if (t < GB * PP) {
        const int idx = blockIdx.x * (GB * PP) + t;
        float f = feat[idx];
        float2 a2 = ((const float2*)ang)[idx];
        float inv = 1.0f / (a2.x*a2.x + a2.y*a2.y);
        nd[t]  = make_float4(f, a2.x, a2.y, 0.0f);
        ndj[t] = make_float4(f, a2.x * inv, a2.y * inv, 0.0f);
    } else if (t >= 512 && t < 832) {
        const int r = t - 512;
        const int slot = r >> 5, sub = r & 31;
        const double* pp = &pacc[slot * NBLK1];
        predl[slot][sub] = pp[sub] + pp[sub+32] + pp[sub+64] + pp[sub+96];
    }

    float v0[5], v1[5], v2[5], v3[5], bb1[5];
#pragma unroll
    for (int o = 0; o < 5; ++o) {
        v0[o] = rfl(W1[o*5+0] - W1[o*5+2]);
        v1[o] = rfl(W1[o*5+1] + W1[o*5+2]);
        v2[o] = rfl(W1[o*5+3]);
        v3[o] = rfl(W1[o*5+4]);
        bb1[o] = rfl(b1[o]);
    }

    __syncthreads();
    if (t < 10) {
        double s = 0.0;
#pragma unroll
        for (int k = 0; k < 32; ++k) s += predl[t][k];
        tmp[t] = s;
    }
    __syncthreads();

    // BN1 folded into layer-1 weights: v' = sc1*v, b' = sc1*b1 + sh1
#pragma unroll
    for (int o = 0; o < 5; ++o) {
        double mu  = tmp[o]   * INV_ETOT;
        double var = tmp[5+o] * INV_ETOT - mu * mu;
        float sc = rfl(g1[o]) * rsqrtf((float)var + EPSF);
        float sh = rfl(rfl(bt1[o]) - (float)mu * sc);
        v0[o] = rfl(v0[o] * sc);
        v1[o] = rfl(v1[o] * sc);
        v2[o] = rfl(v2[o] * sc);
        v3[o] = rfl(v3[o] * sc);
        bb1[o] = rfl(fmaf(bb1[o], sc, sh));
    }

    // edge sweep: thread-group p handles batches {2p, 2p+1}
    const int p  = t / 250;
    const int r  = t - p * 250;
    const int pi = r / 5;
    const int s5 = r - pi * 5;

    float s1[5] = {0.f, 0.f, 0.f, 0.f, 0.f};
    float mm[15];
#pragma unroll
    for (int k = 0; k < 15; ++k) mm[k] = 0.f;

    if (t < 1000) {
#pragma unroll
        for (int g = 0; g < 2; ++g) {
            const int b = p * 2 + g;
            const float4 ni = nd[b*PP + pi];
            const float fi = ni.x, ari = ni.y, aii = ni.z;
            float4 njs[10];
#pragma unroll
            for (int q = 0; q < 10; ++q) njs[q] = ndj[b*PP + s5*10 + q];
#pragma unroll
            for (int q = 0; q < 10; ++q) {
                const float4 nj = njs[q];
                const float dr = fmaf(ari, nj.y,  aii*nj.z);
                const float di = fmaf(aii, nj.y, -ari*nj.z);
                float h1[5];
#pragma unroll
                for (int o = 0; o < 5; ++o) {
                    float y = fmaf(v0[o], fi, fmaf(v1[o], nj.x,
                              fmaf(v2[o], dr, fmaf(v3[o], di, bb1[o]))));
                    h1[o] = lrelu(y);
                }
#pragma unroll
                for (int k = 0; k < 5; ++k) {
                    s1[k] += h1[k];
#pragma unroll
                    for (int l = k; l < 5; ++l) {
                        const int idx = k*5 - (k*(k+1))/2 + l;
                        mm[idx] = fmaf(h1[k], h1[l], mm[idx]);
                    }
                }
            }
        }
    }

    float a[20];
#pragma unroll
    for (int k = 0; k < 5; ++k) a[k] = s1[k];
#pragma unroll
    for (int k = 0; k < 15; ++k) a[5+k] = mm[k];
#pragma unroll
    for (int k = 0; k < 20; ++k) {
        float v = a[k];
#pragma unroll
        for (int off = 32; off > 0; off >>= 1) v += __shfl_down(v, off, 64);
        a[k] = v;
    }
    const int lane = t & 63, wv = t >> 6;
    if (lane == 0) {
#pragma unroll
        for (int k = 0; k < 20; ++k) red[wv][k] = a[k];
    }
    __syncthreads();
    if (t < 20) {
        float s = 0.f;
#pragma unroll
        for (int w = 0; w < 16; ++w) s += red[w][t];
        atomicAdd(&acc[t * NCOPY + (blockIdx.x & (NCOPY-1))], (double)s);
    }
}

// ==== K3: full MLP (BN folded, L3 hoisted), aggregate, rotate, write =======
__global__ __launch_bounds__(TPB) void pass3_kernel(
    const float* __restrict__ pt,
    const float* __restrict__ feat, const float* __restrict__ ang,
    const float* __restrict__ W1, const float* __restrict__ b1,
    const float* __restrict__ g1, const float* __restrict__ bt1,
    const float* __restrict__ W2, const float* __restrict__ b2,
    const float* __restrict__ g2, const float* __restrict__ bt2,
    const float* __restrict__ W3, const float* __restrict__ b3,
    const double* __restrict__ acc, const double* __restrict__ pacc,
    float* __restrict__ out)
{
    __shared__ float4 nd[GB * PP];
    __shared__ float4 ndj[GB * PP];
    __shared__ float spt[GB * PP];
    __shared__ double predl[10][32];
    __shared__ double tmp[30];
    __shared__ float scsh[2][5];      // sc2, sh2
    __shared__ float part[1000][5];
    __shared__ __align__(16) float ob[4 * 350];   // coalesced-write staging
    const int t = threadIdx.x;

    if (t < GB * PP) {
        const int idx = blockIdx.x * (GB * PP) + t;
        float f = feat[idx];
        float2 a2 = ((const float2*)ang)[idx];
        float inv = 1.0f / (a2.x*a2.x + a2.y*a2.y);
        nd[t]  = make_float4(f, a2.x, a2.y, 0.0f);
        ndj[t] = make_float4(f, a2.x * inv, a2.y * inv, 0.0f);
        spt[t] = pt[idx];
    } else if (t >= 512 && t < 832) {
        const int r = t - 512;
        const int slot = r >> 5, sub = r & 31;
        const double* pp = &pacc[slot * NBLK1];
        predl[slot][sub] = pp[sub] + pp[sub+32] + pp[sub+64] + pp[sub+96];
    } else if (t >= 832 && t < 852) {
        const int k = t - 832;
        double s = 0.0;
#pragma unroll
        for (int c = 0; c < NCOPY; ++c) s += acc[k * NCOPY + c];
        tmp[10 + k] = s;
    }

    float v0[5], v1[5], v2[5], v3[5], bb1[5], w2[25], bb2[5], w3[25], bb3[5];
#pragma unroll
    for (int o = 0; o < 5; ++o) {
        v0[o] = rfl(W1[o*5+0] - W1[o*5+2]);
        v1[o] = rfl(W1[o*5+1] + W1[o*5+2]);
        v2[o] = rfl(W1[o*5+3]);
        v3[o] = rfl(W1[o*5+4]);
        bb1[o] = rfl(b1[o]); bb2[o] = rfl(b2[o]); bb3[o] = rfl(b3[o]);
    }
#pragma unroll
    for (int i = 0; i < 25; ++i) { w2[i] = rfl(W2[i]); w3[i] = rfl(W3[i]); }

    __syncthreads();
    if (t < 10) {
        double s = 0.0;
#pragma unroll
        for (int k = 0; k < 32; ++k) s += predl[t][k];
        tmp[t] = s;
    }
    __syncthreads();

    // fold BN1 into layer 1
#pragma unroll
    for (int o = 0; o < 5; ++o) {
        double mu  = tmp[o]   * INV_ETOT;
        double var = tmp[5+o] * INV_ETOT - mu * mu;
        float sc = rfl(g1[o]) * rsqrtf((float)var + EPSF);
        float sh = rfl(rfl(bt1[o]) - (float)mu * sc);
        v0[o] = rfl(v0[o] * sc);
        v1[o] = rfl(v1[o] * sc);
        v2[o] = rfl(v2[o] * sc);
        v3[o] = rfl(v3[o] * sc);
        bb1[o] = rfl(fmaf(bb1[o], sc, sh));
    }

    // BN2 from moments: mu2 = w_o.Sn + b2[o]; var2 = w_o^T Mn w_o - (w_o.Sn)^2
    if (t < 5) {
        const int o = t;
        double w[5], Sn[5];
#pragma unroll
        for (int k = 0; k < 5; ++k) {
            w[k]  = (double)w2[o*5+k];
            Sn[k] = tmp[10+k] * INV_ETOT;
        }
        double muw = 0.0;
#pragma unroll
        for (int k = 0; k < 5; ++k) muw += w[k] * Sn[k];
        double q = 0.0;
#pragma unroll
        for (int k = 0; k < 5; ++k) {
#pragma unroll
            for (int l = k; l < 5; ++l) {
                const int idx = k*5 - (k*(k+1))/2 + l;
                const double Mn = tmp[15+idx] * INV_ETOT;
                q += (k == l ? w[k]*w[k] : 2.0*w[k]*w[l]) * Mn;
            }
        }
        double var2 = q - muw * muw;
        double mu2  = muw + (double)bb2[o];
        float sc2 = g2[o] * rsqrtf((float)var2 + EPSF);
        scsh[0][o] = sc2;
        scsh[1][o] = bt2[o] - (float)mu2 * sc2;
    }
    __syncthreads();

#pragma unroll
    for (int o = 0; o < 5; ++o) {
        const float s2f = rfl(scsh[0][o]);
        const float s2h = rfl(scsh[1][o]);
#pragma unroll
        for (int k = 0; k < 5; ++k) w2[o*5+k] = rfl(w2[o*5+k] * s2f);
        bb2[o] = rfl(fmaf(bb2[o], s2f, s2h));
    }

    // edge sweep: thread-group p handles batches {2p, 2p+1}
    const int p  = t / 250;
    const int r  = t - p * 250;
    const int pi = r / 5;
    const int s5 = r - pi * 5;

#pragma unroll
    for (int g = 0; g < 2; ++g) {
        float a[5] = {0.f, 0.f, 0.f, 0.f, 0.f};
        if (t < 1000) {
            const int b = p * 2 + g;
            const float4 ni = nd[b*PP + pi];
            const float fi = ni.x, ari = ni.y, aii = ni.z;
            float4 njs[10];
#pragma unroll
            for (int q = 0; q < 10; ++q) njs[q] = ndj[b*PP + s5*10 + q];
#pragma unroll
            for (int q = 0; q < 10; ++q) {
                const float4 nj = njs[q];
                const float dr = fmaf(ari, nj.y,  aii*nj.z);
                const float di = fmaf(aii, nj.y, -ari*nj.z);
                float h1[5], h2[5];
#pragma unroll
                for (int o = 0; o < 5; ++o) {
                    float y = fmaf(v0[o], fi, fmaf(v1[o], nj.x,
                              fmaf(v2[o], dr, fmaf(v3[o], di, bb1[o]))));
                    h1[o] = lrelu(y);
                }
#pragma unroll
                for (int o = 0; o < 5; ++o) {
                    float y = bb2[o];
                    y = fmaf(w2[o*5+0], h1[0], y);
                    y = fmaf(w2[o*5+1], h1[1], y);
                    y = fmaf(w2[o*5+2], h1[2], y);
                    y = fmaf(w2[o*5+3], h1[3], y);
                    y = fmaf(w2[o*5+4], h1[4], y);
                    h2[o] = lrelu(y);
                }
#pragma unroll
                for (int o = 0; o < 5; ++o) a[o] += h2[o];
            }
#pragma unroll
            for (int c = 0; c < 5; ++c) part[t][c] = a[c];
        }
        __syncthreads();

        if (t < 1000 && r < PP) {   // one thread per (group, node)
            float hm[5];
#pragma unroll
            for (int c = 0; c < 5; ++c) {
                const int base = p * 250 + 5 * r;
                hm[c] = (part[base][c] + part[base+1][c] + part[base+2][c] +
                         part[base+3][c] + part[base+4][c]) * 0.02f;
            }
            // layer 3 hoisted: mean commutes with affine W3
            float m[5];
#pragma unroll
            for (int c = 0; c < 5; ++c) {
                float y = bb3[c];
                y = fmaf(w3[c*5+0], hm[0], y);
                y = fmaf(w3[c*5+1], hm[1], y);
                y = fmaf(w3[c*5+2], hm[2], y);
                y = fmaf(w3[c*5+3], hm[3], y);
                y = fmaf(w3[c*5+4], hm[4], y);
                m[c] = y;
            }
            const int b = p * 2 + g;
            const int node = b * PP + r;
            const float4 ni = nd[node];
            float ss, cc;
            sincosf(6.2831853071795865f * m[4], &ss, &cc);
            float* o = &ob[p * 350 + r * 7];
            o[0] = spt[node];
            o[1] = m[0];
            o[2] = m[1];
            o[3] = m[2];
            o[4] = m[3];
            o[5] = cc * ni.y - ss * ni.z;
            o[6] = cc * ni.z + ss * ni.y;
        }
        __syncthreads();

        if (t < 700) {   // 4 groups x 350 floats = 700 float2, coalesced
            const int pp = t / 175, k = t - pp * 175;
            float2* dst = (float2*)(out + (size_t)blockIdx.x * (GB * PP * 7)
                                        + (size_t)(pp * 2 + g) * 350);
            dst[k] = ((const float2*)ob)[pp * 175 + k];
        }
        __syncthreads();
    }
}

extern "C" void kernel_launch(void* const* d_in, const int* in_sizes, int n_in,
                              void* d_out, int out_size, void* d_ws, size_t ws_size,
                              hipStream_t stream)
{
    const float* pt   = (const float*)d_in[0];
    const float* feat = (const float*)d_in[1];
    const float* ang  = (const float*)d_in[2];
    const float* W1   = (const float*)d_in[3];
    const float* b1   = (const float*)d_in[4];
    const float* g1   = (const float*)d_in[5];
    const float* bt1  = (const float*)d_in[6];
    const float* W2   = (const float*)d_in[7];
    const float* b2   = (const float*)d_in[8];
    const float* g2   = (const float*)d_in[9];
    const float* bt2  = (const float*)d_in[10];
    const float* W3   = (const float*)d_in[11];
    const float* b3   = (const float*)d_in[12];
    // d_in[13] = edge_index: closed-form structure (dst=b*P+pi, src=b*P+pj), unused
    float* out = (float*)d_out;
    double* acc  = (double*)d_ws;            // 20*NCOPY doubles (K1 blk0 zeroes)
    double* pacc = acc + 20 * NCOPY;         // 10*NBLK1 doubles (plain stores)

    stats1_kernel<<<NBLK1, TPB, 0, stream>>>(feat, ang, W1, b1, acc, pacc);
    pass2_kernel<<<NBLK2, TPB, 0, stream>>>(feat, ang, W1, b1, g1, bt1, acc, pacc);
    pass3_kernel<<<NBLK2, TPB, 0, stream>>>(pt, feat, ang, W1, b1, g1, bt1,
                                            W2, b2, g2, bt2, W3, b3,
                                            acc, pacc, out);
}